// Round 2
// baseline (63.389 us; speedup 1.0000x reference)
//
#include <hip/hip_runtime.h>

#define ALPHA 0.1f
#define LOG2E 1.4426950408889634f

typedef __attribute__((ext_vector_type(8))) short bf16x8;
typedef __attribute__((ext_vector_type(4))) float f32x4;

// round-to-nearest-even f32 -> bf16 (returns bits in low 16)
__device__ __forceinline__ unsigned int f2bf(float f) {
    unsigned int u = __float_as_uint(f);
    return (u + 0x7FFFu + ((u >> 16) & 1u)) >> 16;
}

__global__ void mmd_zero(float* out) { out[0] = 0.f; }

// Block = 256 threads = 4 waves (2x2), block tile = 128x128 pairs, D=64.
// LDS tiles stored as bf16 in K-major 16B-chunk layout: ldsT[buf][kc*128 + row]
// holds elements [row][kc*8 .. kc*8+7].
__global__ __launch_bounds__(256) void mmd_main(const float* __restrict__ x,
                                                const float* __restrict__ y,
                                                float* __restrict__ out, int T) {
    __shared__ uint4 ldsT[4][1024];  // 4 x 16KB bf16 tiles: xI, xJ, yI, yJ
    __shared__ float ldsB[4][128];   // -alpha*log2e * squared-norm per row
    __shared__ float ldsRed[4];

    // block -> upper-triangular (bi, bj), bi <= bj
    int u = blockIdx.x, bi = 0, rem = T;
    while (u >= rem) { u -= rem; ++bi; --rem; }
    int bj = bi + u;
    bool diag = (bi == bj);

    int tid = threadIdx.x;
    int RI = bi * 128, RJ = bj * 128;

    // ---- stage 4 tiles (f32 global -> bf16 LDS, K-major chunks) ----
    const float4* x4 = (const float4*)x;
    const float4* y4 = (const float4*)y;
#pragma unroll
    for (int p = 0; p < 16; ++p) {
        int task = p * 256 + tid;       // 4096 chunk tasks
        int buf = task >> 10;           // 0..3
        int q = task & 1023;
        int row = q >> 3, kc = q & 7;
        int base = (buf & 1) ? RJ : RI;
        const float4* src = (buf < 2) ? x4 : y4;
        float4 a = src[(base + row) * 16 + kc * 2];
        float4 b = src[(base + row) * 16 + kc * 2 + 1];
        uint4 pk;
        pk.x = f2bf(a.x) | (f2bf(a.y) << 16);
        pk.y = f2bf(a.z) | (f2bf(a.w) << 16);
        pk.z = f2bf(b.x) | (f2bf(b.y) << 16);
        pk.w = f2bf(b.z) | (f2bf(b.w) << 16);
        ldsT[buf][kc * 128 + row] = pk;
    }
    __syncthreads();

    // ---- per-row squared norms of the bf16 data -> log2-domain bias ----
#pragma unroll
    for (int p = 0; p < 2; ++p) {
        int task = p * 256 + tid;       // 512 rows total
        int buf = task >> 7, row = task & 127;
        float s = 0.f;
#pragma unroll
        for (int kc = 0; kc < 8; ++kc) {
            uint4 v = ldsT[buf][kc * 128 + row];
            unsigned int wds[4] = {v.x, v.y, v.z, v.w};
#pragma unroll
            for (int i = 0; i < 4; ++i) {
                float lo = __uint_as_float(wds[i] << 16);
                float hi = __uint_as_float(wds[i] & 0xFFFF0000u);
                s = fmaf(lo, lo, s);
                s = fmaf(hi, hi, s);
            }
        }
        ldsB[buf][row] = -ALPHA * LOG2E * s;
    }
    __syncthreads();

    int w = tid >> 6, l = tid & 63;
    int wr = w >> 1, wc = w & 1;          // 2x2 waves, each 64x64 output
    int lrow = l & 15, lk = l >> 4;

    // passes: K(xI,xJ), L(yI,yJ), P(xI,yJ), P'(xJ,yI) [off-diag only]
    const int aBufs[4] = {0, 2, 0, 1};
    const int bBufs[4] = {1, 3, 3, 2};
    float wKL = diag ? 1.f : 2.f;
    const float wts[4] = {wKL, wKL, -2.f, -2.f};
    int npass = diag ? 3 : 4;

    const float C2 = 2.f * ALPHA * LOG2E;
    float stot = 0.f;

    for (int ps = 0; ps < npass; ++ps) {
        int ab = aBufs[ps], bb = bBufs[ps];

        // fragment loads: lane l takes row (l&15), k-chunk (l>>4) per 16x16x32
        bf16x8 af[4][2], bfr[4][2];
#pragma unroll
        for (int mb = 0; mb < 4; ++mb) {
#pragma unroll
            for (int kh = 0; kh < 2; ++kh) {
                int ar = wr * 64 + mb * 16 + lrow;
                int br = wc * 64 + mb * 16 + lrow;
                int kc = kh * 4 + lk;
                af[mb][kh]  = *(const bf16x8*)&ldsT[ab][kc * 128 + ar];
                bfr[mb][kh] = *(const bf16x8*)&ldsT[bb][kc * 128 + br];
            }
        }

        f32x4 acc[4][4];
#pragma unroll
        for (int mb = 0; mb < 4; ++mb)
#pragma unroll
            for (int nb = 0; nb < 4; ++nb)
                acc[mb][nb] = (f32x4){0.f, 0.f, 0.f, 0.f};

#pragma unroll
        for (int mb = 0; mb < 4; ++mb) {
#pragma unroll
            for (int nb = 0; nb < 4; ++nb) {
                acc[mb][nb] = __builtin_amdgcn_mfma_f32_16x16x32_bf16(
                    af[mb][0], bfr[nb][0], acc[mb][nb], 0, 0, 0);
                acc[mb][nb] = __builtin_amdgcn_mfma_f32_16x16x32_bf16(
                    af[mb][1], bfr[nb][1], acc[mb][nb], 0, 0, 0);
            }
        }

        // epilogue: term = 2^(C2*dot + bA_row + bB_col)
        float bA[4][4], bB[4];
#pragma unroll
        for (int mb = 0; mb < 4; ++mb)
#pragma unroll
            for (int q = 0; q < 4; ++q)
                bA[mb][q] = ldsB[ab][wr * 64 + mb * 16 + lk * 4 + q];
#pragma unroll
        for (int nb = 0; nb < 4; ++nb)
            bB[nb] = ldsB[bb][wc * 64 + nb * 16 + lrow];

        float sp = 0.f;
#pragma unroll
        for (int mb = 0; mb < 4; ++mb) {
#pragma unroll
            for (int nb = 0; nb < 4; ++nb) {
#pragma unroll
                for (int q = 0; q < 4; ++q) {
                    float arg = fmaf(C2, acc[mb][nb][q], bA[mb][q] + bB[nb]);
                    sp += __builtin_amdgcn_exp2f(arg);
                }
            }
        }
        stot = fmaf(wts[ps], sp, stot);
    }

    // ---- reduce: wave shuffle -> LDS -> one atomic per block ----
#pragma unroll
    for (int off = 32; off > 0; off >>= 1)
        stot += __shfl_down(stot, off, 64);
    if (l == 0) ldsRed[w] = stot;
    __syncthreads();
    if (tid == 0)
        atomicAdd(out, ldsRed[0] + ldsRed[1] + ldsRed[2] + ldsRed[3]);
}

extern "C" void kernel_launch(void* const* d_in, const int* in_sizes, int n_in,
                              void* d_out, int out_size, void* d_ws, size_t ws_size,
                              hipStream_t stream) {
    (void)n_in; (void)out_size; (void)d_ws; (void)ws_size;
    const float* x = (const float*)d_in[0];
    const float* y = (const float*)d_in[1];
    float* out = (float*)d_out;

    int N = in_sizes[0] / 64;   // 8192
    int T = N / 128;            // 64 tiles per side
    int nblocks = T * (T + 1) / 2;

    hipLaunchKernelGGL(mmd_zero, dim3(1), dim3(1), 0, stream, out);
    hipLaunchKernelGGL(mmd_main, dim3(nblocks), dim3(256), 0, stream, x, y, out, T);
}